// Round 4
// baseline (878.482 us; speedup 1.0000x reference)
//
#include <hip/hip_runtime.h>
#include <hip/hip_bf16.h>
#include <stdint.h>

typedef __bf16 bf16;
typedef __bf16 bf16x8 __attribute__((ext_vector_type(8)));
typedef __bf16 bf16x4 __attribute__((ext_vector_type(4)));
typedef float  floatx16 __attribute__((ext_vector_type(16)));

#define DIMD 2048
#define BATB 4
#define SEQS 4096
#define MTOT (BATB*SEQS)   // 16384

#define BAR()    __builtin_amdgcn_s_barrier()
#define LGKMC(N) asm volatile("s_waitcnt lgkmcnt(" #N ")" ::: "memory")
#define VMC4()   asm volatile("s_waitcnt vmcnt(4)" ::: "memory")
#define VMC0()   asm volatile("s_waitcnt vmcnt(0)" ::: "memory")
#define SCHED0() __builtin_amdgcn_sched_barrier(0)

__device__ __forceinline__ void gload_lds16(const bf16* g, bf16* l) {
    __builtin_amdgcn_global_load_lds(
        (const __attribute__((address_space(1))) void*)g,
        (__attribute__((address_space(3))) void*)l,
        16, 0, 0);
}

// ---------------- fp32 -> bf16 convert (weights) ----------------
__global__ __launch_bounds__(256) void f2bf_k(const float* __restrict__ src,
                                              bf16* __restrict__ dst, int n) {
    int i = (blockIdx.x * 256 + threadIdx.x) * 4;
    if (i >= n) return;
    float4 v = *(const float4*)&src[i];
    bf16x4 o;
    o[0] = (bf16)v.x; o[1] = (bf16)v.y; o[2] = (bf16)v.z; o[3] = (bf16)v.w;
    *(bf16x4*)&dst[i] = o;
}

// ---------------- RMSNorm: fp32 [M,2048] -> bf16 [M,2048] ----------------
__global__ __launch_bounds__(256) void rmsnorm_k(const float* __restrict__ x,
                                                 bf16* __restrict__ xn) {
    const int row = blockIdx.x;
    const int tid = threadIdx.x;
    const float* xr = x + (size_t)row * DIMD;
    float4 a = *(const float4*)&xr[tid * 8];
    float4 b = *(const float4*)&xr[tid * 8 + 4];
    float s = a.x*a.x + a.y*a.y + a.z*a.z + a.w*a.w
            + b.x*b.x + b.y*b.y + b.z*b.z + b.w*b.w;
    #pragma unroll
    for (int off = 32; off > 0; off >>= 1) s += __shfl_down(s, off);
    __shared__ float red[4];
    if ((tid & 63) == 0) red[tid >> 6] = s;
    __syncthreads();
    float tot = red[0] + red[1] + red[2] + red[3];
    float sc = rsqrtf(tot * (1.0f / DIMD) + 1.1920929e-07f);
    bf16x8 o;
    o[0] = (bf16)(a.x * sc); o[1] = (bf16)(a.y * sc);
    o[2] = (bf16)(a.z * sc); o[3] = (bf16)(a.w * sc);
    o[4] = (bf16)(b.x * sc); o[5] = (bf16)(b.y * sc);
    o[6] = (bf16)(b.z * sc); o[7] = (bf16)(b.w * sc);
    *(bf16x8*)&xn[(size_t)row * DIMD + tid * 8] = o;
}

// ---------------- gating + causal depthwise conv ----------------
__global__ __launch_bounds__(256) void gateconv_k(const bf16* __restrict__ h,
                                                  const float* __restrict__ cw,
                                                  const float* __restrict__ cb,
                                                  bf16* __restrict__ o,
                                                  const int* __restrict__ dil_p) {
    int gid = blockIdx.x * 256 + threadIdx.x;
    int m = gid >> 9;            // 512 groups of 4 dims per row
    int d = (gid & 511) << 2;
    int s = m & (SEQS - 1);
    int dil = dil_p[0];
    const bf16* hr = h + (size_t)m * (3 * DIMD);

    bf16x4 Cv = __builtin_nontemporal_load((const bf16x4*)&hr[DIMD + d]);
    bf16x4 B0 = *(const bf16x4*)&hr[d];
    bf16x4 Z0 = *(const bf16x4*)&hr[2 * DIMD + d];
    float y0[4], y1[4], y2[4];
    #pragma unroll
    for (int j = 0; j < 4; ++j) y0[j] = (float)B0[j] * (float)Z0[j];
    if (s >= dil) {
        const bf16* h1 = hr - (size_t)dil * 3 * DIMD;
        bf16x4 B1 = *(const bf16x4*)&h1[d];
        bf16x4 Z1 = *(const bf16x4*)&h1[2 * DIMD + d];
        #pragma unroll
        for (int j = 0; j < 4; ++j) y1[j] = (float)B1[j] * (float)Z1[j];
    } else {
        #pragma unroll
        for (int j = 0; j < 4; ++j) y1[j] = 0.0f;
    }
    if (s >= 2 * dil) {
        const bf16* h2 = hr - (size_t)(2 * dil) * 3 * DIMD;
        bf16x4 B2 = *(const bf16x4*)&h2[d];
        bf16x4 Z2 = *(const bf16x4*)&h2[2 * DIMD + d];
        #pragma unroll
        for (int j = 0; j < 4; ++j) y2[j] = (float)B2[j] * (float)Z2[j];
    } else {
        #pragma unroll
        for (int j = 0; j < 4; ++j) y2[j] = 0.0f;
    }
    bf16x4 ov;
    #pragma unroll
    for (int j = 0; j < 4; ++j) {
        float w0 = cw[(d + j) * 3 + 0];
        float w1 = cw[(d + j) * 3 + 1];
        float w2 = cw[(d + j) * 3 + 2];
        float conv = w0 * y2[j] + w1 * y1[j] + w2 * y0[j] + cb[d + j];
        ov[j] = (bf16)((float)Cv[j] * conv);
    }
    *(bf16x4*)&o[(size_t)m * DIMD + d] = ov;
}

// ---------------- NT bf16 GEMM: C[M,N] = A[M,K] * B[N,K]^T ----------------
// 256x256 tile, BK=64, 8 waves (2M x 4N), v_mfma_f32_32x32x16_bf16, TWO
// phases per K-tile (4 barriers/tile), counted vmcnt/lgkmcnt.
// Per wave: 128x64 output = 4m x 2n frags of 32x32; K-tile = 4 kslices of 16.
// Reads (ds_read_b128): R1 = B(t) all ks [8] + A(t) ks0,ks1 [8], issued at
// pB(t-1) tail after VMC4+BAR certify buf(t); R2 = A(t) ks2,ks3 [8] at pA(t).
// Waits: pA lgkmcnt(8) (R1 done, R2 in flight), pB lgkmcnt(0) (R2 done).
// Stages (global_load_lds x2 per half): pA: Ah0,Ah1(t+1)->other buf (A(t-1)
// last-read certified at pB(t-1) end-bar); pB: Bh0,Bh1(t+2)->cur buf (B(t)
// last-read certified at pA(t) end-bar). VMC4 at pB: outstanding =
// {Ah(t+1)[4], Bh(t+2)[4]} -> leave newest 4 => tile t+1 fully in LDS before
// R1(t+1). LDS chunk-XOR swizzle (slot = chunk ^ (row&7)) via pre-swizzled
// global source; 32-row b128 reads are 2-way-per-slot = conflict-free.
// C/D map (m74/m101): col=lane&31, row=(reg&3)+8*(reg>>2)+4*(lane>>5).
template<int RESID>
__global__ __launch_bounds__(512, 2) void gemm_bt(const bf16* __restrict__ A,
                                                  const bf16* __restrict__ B,
                                                  bf16* __restrict__ Hout,
                                                  float* __restrict__ Fout,
                                                  const float* __restrict__ resid,
                                                  const float* __restrict__ scale,
                                                  int M, int N, int K) {
    __shared__ __align__(16) bf16 smem[2][32768];   // [buf][A 16384 | B 16384]
    const int tid = threadIdx.x;
    const int wave = tid >> 6;
    const int lane = tid & 63;
    const int l31 = lane & 31;
    const int hi = lane >> 5;
    const int l7 = lane & 7;

    // bijective XCD-aware swizzle (nwg % 8 == 0 for both launches)
    const int nx   = (int)gridDim.x;
    const int nwg  = nx * (int)gridDim.y;
    const int orig = (int)blockIdx.y * nx + (int)blockIdx.x;
    const int lin  = (orig & 7) * (nwg >> 3) + (orig >> 3);
    const int n0 = (lin % nx) * 256;
    const int m0 = (lin / nx) * 256;

    const int wm = (wave >> 2) * 128;   // wave's 128-row half of the A tile
    const int wn = (wave & 3) * 64;     // wave's 64-row slice of the B tile

    // staging: thread covers row srow, chunk (tid&7); fetches global chunk
    // cs = c ^ (row&7) so the linear LDS dest realizes the swizzle
    const int srow = tid >> 3;                 // 0..63
    const int cs   = (tid & 7) ^ (srow & 7);
    const bf16* aSrc = A + (size_t)(m0 + srow) * K + cs * 8;
    const bf16* bSrc = B + (size_t)(n0 + srow) * K + cs * 8;
    const int stbase = wave * 512;             // wave-uniform LDS element base
    const size_t K64  = (size_t)K * 64;
    const size_t K128 = (size_t)K * 128;

    // ds_read addressing: frag row = base + l31; chunk = ks*2 + hi;
    // swizzled slot = chunk ^ (row&7) with row&7 == l7 (bases are mult of 8)
    const int arow = (wm + l31) * 64;
    const int brow = (wn + l31) * 64;
    const int slotk[4] = { ((0 + hi) ^ l7) * 8, ((2 + hi) ^ l7) * 8,
                           ((4 + hi) ^ l7) * 8, ((6 + hi) ^ l7) * 8 };

    bf16x8 Afr[4][4];                          // [kslice][m-frag]
    bf16x8 Bfr[4][2];                          // [kslice][n-frag]
    floatx16 acc[4][2];                        // [m-frag][n-frag]
    #pragma unroll
    for (int mi = 0; mi < 4; ++mi)
        #pragma unroll
        for (int ni = 0; ni < 2; ++ni) acc[mi][ni] = (floatx16)0.0f;

    auto stage = [&](const bf16* src, bf16* dstBase, int t, int h) {
        const bf16* s = src + (size_t)h * K128 + (size_t)t * 64;
        bf16* d = dstBase + h * 8192 + stbase;
        gload_lds16(s, d);
        gload_lds16(s + K64, d + 4096);
    };
    auto ldAk = [&](const bf16* Asb, int ks) {
        #pragma unroll
        for (int mi = 0; mi < 4; ++mi)
            Afr[ks][mi] = *(const bf16x8*)(Asb + arow + mi * (32 * 64) + slotk[ks]);
    };
    auto ldBk = [&](const bf16* Bsb, int ks) {
        #pragma unroll
        for (int ni = 0; ni < 2; ++ni)
            Bfr[ks][ni] = *(const bf16x8*)(Bsb + brow + ni * (32 * 64) + slotk[ks]);
    };
    auto mmk = [&](int ks) {
        #pragma unroll
        for (int mi = 0; mi < 4; ++mi)
            #pragma unroll
            for (int ni = 0; ni < 2; ++ni)
                acc[mi][ni] = __builtin_amdgcn_mfma_f32_32x32x16_bf16(
                    Afr[ks][mi], Bfr[ks][ni], acc[mi][ni], 0, 0, 0);
    };

    const int NT = K >> 6;   // 32 for K=2048

    // prologue: A(0),B(0),B(1); VMC4 leaves B(1) => tile0 landed
    stage(aSrc, smem[0],         0, 0);
    stage(aSrc, smem[0],         0, 1);
    stage(bSrc, smem[0] + 16384, 0, 0);
    stage(bSrc, smem[0] + 16384, 0, 1);
    stage(bSrc, smem[1] + 16384, 1, 0);
    stage(bSrc, smem[1] + 16384, 1, 1);
    VMC4();
    BAR();
    // R1(0): all B + A ks0,ks1
    ldBk(smem[0] + 16384, 0); ldBk(smem[0] + 16384, 1);
    ldBk(smem[0] + 16384, 2); ldBk(smem[0] + 16384, 3);
    ldAk(smem[0], 0); ldAk(smem[0], 1);
    SCHED0();

    for (int t = 0; t < NT - 2; ++t) {
        const int b = t & 1;
        const bf16* Acur = smem[b];
        bf16* Bwr = smem[b] + 16384;
        bf16* Aoth = smem[b ^ 1];
        const bf16* Anxt = smem[b ^ 1];
        const bf16* Bnxt = smem[b ^ 1] + 16384;
        // ---- pA: R2 reads; stage A(t+1)->other; wait R1; mm ks0,ks1
        ldAk(Acur, 2); ldAk(Acur, 3);
        stage(aSrc, Aoth, t + 1, 0);
        stage(aSrc, Aoth, t + 1, 1);
        SCHED0(); BAR(); LGKMC(8); SCHED0();
        __builtin_amdgcn_s_setprio(1);
        mmk(0); mmk(1);
        __builtin_amdgcn_s_setprio(0);
        BAR();
        // ---- pB: stage B(t+2)->cur; VMC4 => tile t+1 landed; wait R2;
        //          mm ks2,ks3; then R1(t+1) into dead regs
        stage(bSrc, Bwr, t + 2, 0);
        stage(bSrc, Bwr, t + 2, 1);
        VMC4();
        BAR(); LGKMC(0); SCHED0();
        __builtin_amdgcn_s_setprio(1);
        mmk(2); mmk(3);
        __builtin_amdgcn_s_setprio(0);
        SCHED0();
        ldBk(Bnxt, 0); ldBk(Bnxt, 1); ldBk(Bnxt, 2); ldBk(Bnxt, 3);
        ldAk(Anxt, 0); ldAk(Anxt, 1);
        SCHED0(); BAR();
    }
    {   // tile NT-2: pA stages A(NT-1); pB no B stage, drain vmcnt to 0
        const int t = NT - 2;
        const int b = t & 1;
        const bf16* Acur = smem[b];
        bf16* Aoth = smem[b ^ 1];
        const bf16* Anxt = smem[b ^ 1];
        const bf16* Bnxt = smem[b ^ 1] + 16384;
        ldAk(Acur, 2); ldAk(Acur, 3);
        stage(aSrc, Aoth, t + 1, 0);
        stage(aSrc, Aoth, t + 1, 1);
        SCHED0(); BAR(); LGKMC(8); SCHED0();
        __builtin_amdgcn_s_setprio(1);
        mmk(0); mmk(1);
        __builtin_amdgcn_s_setprio(0);
        BAR();
        VMC0();                               // A(NT-1) (and all older) landed
        BAR(); LGKMC(0); SCHED0();
        __builtin_amdgcn_s_setprio(1);
        mmk(2); mmk(3);
        __builtin_amdgcn_s_setprio(0);
        SCHED0();
        ldBk(Bnxt, 0); ldBk(Bnxt, 1); ldBk(Bnxt, 2); ldBk(Bnxt, 3);
        ldAk(Anxt, 0); ldAk(Anxt, 1);
        SCHED0(); BAR();
    }
    {   // tile NT-1: no staging, no vmcnt
        const int b = (NT - 1) & 1;
        const bf16* Acur = smem[b];
        ldAk(Acur, 2); ldAk(Acur, 3);
        SCHED0(); BAR(); LGKMC(8); SCHED0();
        __builtin_amdgcn_s_setprio(1);
        mmk(0); mmk(1);
        __builtin_amdgcn_s_setprio(0);
        LGKMC(0); SCHED0();
        __builtin_amdgcn_s_setprio(1);
        mmk(2); mmk(3);
        __builtin_amdgcn_s_setprio(0);
    }

    // epilogue: 32x32 C/D map col=lane&31, row=(reg&3)+8*(reg>>2)+4*(lane>>5)
    #pragma unroll
    for (int mi = 0; mi < 4; ++mi)
        #pragma unroll
        for (int ni = 0; ni < 2; ++ni) {
            const int c  = n0 + wn + ni * 32 + l31;
            const int rb = m0 + wm + mi * 32 + 4 * hi;
            #pragma unroll
            for (int reg = 0; reg < 16; ++reg) {
                const int r = rb + (reg & 3) + 8 * (reg >> 2);
                size_t off = (size_t)r * N + c;
                float v = acc[mi][ni][reg];
                if (RESID) {
                    float rv = __builtin_nontemporal_load(&resid[off]);
                    __builtin_nontemporal_store(rv + scale[c] * v, &Fout[off]);
                } else {
                    __builtin_nontemporal_store((bf16)v, &Hout[off]);
                }
            }
        }
}

extern "C" void kernel_launch(void* const* d_in, const int* in_sizes, int n_in,
                              void* d_out, int out_size, void* d_ws, size_t ws_size,
                              hipStream_t stream) {
    const float* x  = (const float*)d_in[0];
    const float* We = (const float*)d_in[1];
    const float* cw = (const float*)d_in[2];
    const float* cb = (const float*)d_in[3];
    const float* Wp = (const float*)d_in[4];
    const float* cs = (const float*)d_in[5];
    const int*   dil = (const int*)d_in[6];

    char* ws = (char*)d_ws;
    bf16* xn  = (bf16*)ws;                                  // 67108864 B (reused for o)
    bf16* Web = (bf16*)(ws + 67108864);                     // 25165824 B
    bf16* Wpb = (bf16*)(ws + 67108864 + 25165824);          // 8388608 B
    bf16* h   = (bf16*)(ws + 100663296);                    // 201326592 B

    f2bf_k<<<(3 * DIMD * DIMD / 4 + 255) / 256, 256, 0, stream>>>(We, Web, 3 * DIMD * DIMD);
    f2bf_k<<<(DIMD * DIMD / 4 + 255) / 256, 256, 0, stream>>>(Wp, Wpb, DIMD * DIMD);
    rmsnorm_k<<<MTOT, 256, 0, stream>>>(x, xn);
    gemm_bt<0><<<dim3(3 * DIMD / 256, MTOT / 256), 512, 0, stream>>>(
        xn, Web, h, nullptr, nullptr, nullptr, MTOT, 3 * DIMD, DIMD);
    gateconv_k<<<(MTOT * (DIMD / 4)) / 256, 256, 0, stream>>>(h, cw, cb, xn /*o*/, dil);
    gemm_bt<1><<<dim3(DIMD / 256, MTOT / 256), 512, 0, stream>>>(
        xn /*o*/, Wpb, nullptr, (float*)d_out, x, cs, MTOT, DIMD, DIMD);
}

// Round 5
// 825.712 us; speedup vs baseline: 1.0639x; 1.0639x over previous
//
#include <hip/hip_runtime.h>
#include <hip/hip_bf16.h>
#include <stdint.h>

typedef __bf16 bf16;
typedef __bf16 bf16x8 __attribute__((ext_vector_type(8)));
typedef __bf16 bf16x4 __attribute__((ext_vector_type(4)));
typedef float  floatx4 __attribute__((ext_vector_type(4)));

#define DIMD 2048
#define BATB 4
#define SEQS 4096
#define MTOT (BATB*SEQS)   // 16384

#define BAR()    __builtin_amdgcn_s_barrier()
#define LGKMC(N) asm volatile("s_waitcnt lgkmcnt(" #N ")" ::: "memory")
#define VMC6()   asm volatile("s_waitcnt vmcnt(6)" ::: "memory")
#define VMC0()   asm volatile("s_waitcnt vmcnt(0)" ::: "memory")
#define SCHED0() __builtin_amdgcn_sched_barrier(0)

__device__ __forceinline__ void gload_lds16(const bf16* g, bf16* l) {
    __builtin_amdgcn_global_load_lds(
        (const __attribute__((address_space(1))) void*)g,
        (__attribute__((address_space(3))) void*)l,
        16, 0, 0);
}

// ---------------- fp32 -> bf16 convert (weights) ----------------
__global__ __launch_bounds__(256) void f2bf_k(const float* __restrict__ src,
                                              bf16* __restrict__ dst, int n) {
    int i = (blockIdx.x * 256 + threadIdx.x) * 4;
    if (i >= n) return;
    float4 v = *(const float4*)&src[i];
    bf16x4 o;
    o[0] = (bf16)v.x; o[1] = (bf16)v.y; o[2] = (bf16)v.z; o[3] = (bf16)v.w;
    *(bf16x4*)&dst[i] = o;
}

// ---------------- RMSNorm: fp32 [M,2048] -> bf16 [M,2048] ----------------
__global__ __launch_bounds__(256) void rmsnorm_k(const float* __restrict__ x,
                                                 bf16* __restrict__ xn) {
    const int row = blockIdx.x;
    const int tid = threadIdx.x;
    const float* xr = x + (size_t)row * DIMD;
    float4 a = *(const float4*)&xr[tid * 8];
    float4 b = *(const float4*)&xr[tid * 8 + 4];
    float s = a.x*a.x + a.y*a.y + a.z*a.z + a.w*a.w
            + b.x*b.x + b.y*b.y + b.z*b.z + b.w*b.w;
    #pragma unroll
    for (int off = 32; off > 0; off >>= 1) s += __shfl_down(s, off);
    __shared__ float red[4];
    if ((tid & 63) == 0) red[tid >> 6] = s;
    __syncthreads();
    float tot = red[0] + red[1] + red[2] + red[3];
    float sc = rsqrtf(tot * (1.0f / DIMD) + 1.1920929e-07f);
    bf16x8 o;
    o[0] = (bf16)(a.x * sc); o[1] = (bf16)(a.y * sc);
    o[2] = (bf16)(a.z * sc); o[3] = (bf16)(a.w * sc);
    o[4] = (bf16)(b.x * sc); o[5] = (bf16)(b.y * sc);
    o[6] = (bf16)(b.z * sc); o[7] = (bf16)(b.w * sc);
    *(bf16x8*)&xn[(size_t)row * DIMD + tid * 8] = o;
}

// ---------------- gating + causal depthwise conv (tiled, halo-in-register) --
// Block = 16 consecutive m-rows x full D. 256 threads, thread owns an 8-dim
// slice (16B loads/stores, fully coalesced). For dil==1 the conv history
// y[s-1], y[s-2] rotates in registers (2 halo row-loads per block); h's B/z
// planes are then read exactly once (+1/8 halo) instead of ~3x across XCDs.
// General dil falls back to the gather path (uniform branch on dil).
__global__ __launch_bounds__(256) void gateconv_k(const bf16* __restrict__ h,
                                                  const float* __restrict__ cw,
                                                  const float* __restrict__ cb,
                                                  bf16* __restrict__ o,
                                                  const int* __restrict__ dil_p) {
    const int tid = threadIdx.x;
    const int d = tid * 8;
    const int m0 = blockIdx.x * 16;
    const int s0 = m0 & (SEQS - 1);
    const int dil = dil_p[0];

    float w0[8], w1[8], w2[8], bias[8];
    #pragma unroll
    for (int j = 0; j < 8; ++j) {
        w0[j]   = cw[(d + j) * 3 + 0];
        w1[j]   = cw[(d + j) * 3 + 1];
        w2[j]   = cw[(d + j) * 3 + 2];
        bias[j] = cb[d + j];
    }

    if (dil == 1) {
        float y1[8], y2[8];   // y[s-1], y[s-2]
        if (s0 >= 1) {        // s0 is a multiple of 16, so s0>=1 => s0>=2
            const bf16* hp = h + (size_t)(m0 - 1) * (3 * DIMD);
            bf16x8 Bv = *(const bf16x8*)&hp[d];
            bf16x8 Zv = *(const bf16x8*)&hp[2 * DIMD + d];
            #pragma unroll
            for (int j = 0; j < 8; ++j) y1[j] = (float)Bv[j] * (float)Zv[j];
            const bf16* hq = h + (size_t)(m0 - 2) * (3 * DIMD);
            bf16x8 Bw = *(const bf16x8*)&hq[d];
            bf16x8 Zw = *(const bf16x8*)&hq[2 * DIMD + d];
            #pragma unroll
            for (int j = 0; j < 8; ++j) y2[j] = (float)Bw[j] * (float)Zw[j];
        } else {
            #pragma unroll
            for (int j = 0; j < 8; ++j) { y1[j] = 0.0f; y2[j] = 0.0f; }
        }
        for (int r = 0; r < 16; ++r) {
            const bf16* hr = h + (size_t)(m0 + r) * (3 * DIMD);
            bf16x8 Bv = *(const bf16x8*)&hr[d];
            bf16x8 Zv = *(const bf16x8*)&hr[2 * DIMD + d];
            bf16x8 Cv = *(const bf16x8*)&hr[DIMD + d];
            float y0[8];
            bf16x8 ov;
            #pragma unroll
            for (int j = 0; j < 8; ++j) {
                y0[j] = (float)Bv[j] * (float)Zv[j];
                float conv = w0[j] * y2[j] + w1[j] * y1[j] + w2[j] * y0[j] + bias[j];
                ov[j] = (bf16)((float)Cv[j] * conv);
            }
            *(bf16x8*)&o[(size_t)(m0 + r) * DIMD + d] = ov;
            #pragma unroll
            for (int j = 0; j < 8; ++j) { y2[j] = y1[j]; y1[j] = y0[j]; }
        }
    } else {
        for (int r = 0; r < 16; ++r) {
            const int m = m0 + r;
            const int s = m & (SEQS - 1);
            const bf16* hr = h + (size_t)m * (3 * DIMD);
            bf16x8 Bv = *(const bf16x8*)&hr[d];
            bf16x8 Zv = *(const bf16x8*)&hr[2 * DIMD + d];
            bf16x8 Cv = *(const bf16x8*)&hr[DIMD + d];
            float y0[8], y1[8], y2[8];
            #pragma unroll
            for (int j = 0; j < 8; ++j) y0[j] = (float)Bv[j] * (float)Zv[j];
            if (s >= dil) {
                const bf16* h1 = hr - (size_t)dil * 3 * DIMD;
                bf16x8 B1 = *(const bf16x8*)&h1[d];
                bf16x8 Z1 = *(const bf16x8*)&h1[2 * DIMD + d];
                #pragma unroll
                for (int j = 0; j < 8; ++j) y1[j] = (float)B1[j] * (float)Z1[j];
            } else {
                #pragma unroll
                for (int j = 0; j < 8; ++j) y1[j] = 0.0f;
            }
            if (s >= 2 * dil) {
                const bf16* h2 = hr - (size_t)(2 * dil) * 3 * DIMD;
                bf16x8 B2 = *(const bf16x8*)&h2[d];
                bf16x8 Z2 = *(const bf16x8*)&h2[2 * DIMD + d];
                #pragma unroll
                for (int j = 0; j < 8; ++j) y2[j] = (float)B2[j] * (float)Z2[j];
            } else {
                #pragma unroll
                for (int j = 0; j < 8; ++j) y2[j] = 0.0f;
            }
            bf16x8 ov;
            #pragma unroll
            for (int j = 0; j < 8; ++j) {
                float conv = w0[j] * y2[j] + w1[j] * y1[j] + w2[j] * y0[j] + bias[j];
                ov[j] = (bf16)((float)Cv[j] * conv);
            }
            *(bf16x8*)&o[(size_t)m * DIMD + d] = ov;
        }
    }
}

// ---------------- NT bf16 GEMM: C[M,N] = A[M,K] * B[N,K]^T ----------------
// 256x256 tile, BK=64, 8 waves (2M x 4N). R1 skeleton + ROTATING
// ONE-PHASE-AHEAD REGISTER PREFETCH (R3, measured 366us / MfmaUtil 51.5 /
// 0 bank conflicts):
//   p3(t-1) tail (after mm3, regs dead, buffer t certified by VMC6+BAR):
//       read B(t) all 4 frags (8 ds_reads) + A-quad0(t) (4 reads)
//   p0(t): read q1(t);  wait LGKMC(4)  -> B+q0 landed; mm0
//   p1(t): read q2(t);  wait LGKMC(4)  -> q1 landed;   mm1
//   p2(t): read q3(t);  wait LGKMC(4)  -> q2 landed;   mm2
//   p3(t):              wait LGKMC(0)  -> q3 landed;   mm3; tail reads t+1
// Staging: p0 Ah1(t+1)->other buf, p1 Bh0(t+2)->cur, p2 Bh1(t+2)->cur,
// p3 Ah0(t+2)->cur, then VMC6 (leaves exactly {Bh0,Bh1,Ah0}(t+2) in flight
// => tile t+1 fully landed). LDS chunk-XOR swizzle (slot = chunk ^ (row&7))
// via pre-swizzled global source (0 bank conflicts, measured).
// NOTE (R4 lesson): 16x16x32 fragment reads (rows span 16 values, chunk
// varies with lane>>4) are the conflict-free pattern; 32x32x16 (32-row span)
// pigeonholes to >=4-way. Scalar nontemporal bf16 stores amplify WRITE_SIZE
// (partial 64B sectors) — plain stores here.
template<int RESID>
__global__ __launch_bounds__(512, 2) void gemm_bt(const bf16* __restrict__ A,
                                                  const bf16* __restrict__ B,
                                                  bf16* __restrict__ Hout,
                                                  float* __restrict__ Fout,
                                                  const float* __restrict__ resid,
                                                  const float* __restrict__ scale,
                                                  int M, int N, int K) {
    __shared__ __align__(16) bf16 smem[2][32768];   // [buf][A 16384 | B 16384]
    const int tid = threadIdx.x;
    const int wave = tid >> 6;
    const int lane = tid & 63;
    const int quad = lane >> 4;
    const int col16 = lane & 15;

    // bijective XCD-aware swizzle (nwg % 8 == 0 for both launches)
    const int nx   = (int)gridDim.x;
    const int nwg  = nx * (int)gridDim.y;
    const int orig = (int)blockIdx.y * nx + (int)blockIdx.x;
    const int lin  = (orig & 7) * (nwg >> 3) + (orig >> 3);
    const int n0 = (lin % nx) * 256;
    const int m0 = (lin / nx) * 256;

    const int wm = (wave >> 2) * 128;   // wave's 128-row half of the A tile
    const int wn = (wave & 3) * 64;     // wave's 64-row slice of the B tile

    // staging: thread covers row srow, chunk (tid&7); fetches global chunk
    // cs = c ^ (row&7) so the linear LDS dest realizes the swizzle
    const int srow = tid >> 3;                 // 0..63
    const int cs   = (tid & 7) ^ (srow & 7);
    const bf16* aSrc = A + (size_t)(m0 + srow) * K + cs * 8;
    const bf16* bSrc = B + (size_t)(n0 + srow) * K + cs * 8;
    const int stbase = wave * 512;             // wave-uniform LDS element base
    const size_t K64  = (size_t)K * 64;
    const size_t K128 = (size_t)K * 128;

    // ds_read addressing
    const int rsw = col16 & 7;
    const int ard = (wm + col16) * 64;
    const int brd = (wn + col16) * 64;
    const int sl0 = ((0 + quad) ^ rsw) * 8;    // k-slice 0 swizzled slot
    const int sl1 = ((4 + quad) ^ rsw) * 8;    // k-slice 1

    bf16x8 Bf[4][2];                           // current tile's B frags
    bf16x8 A0[2][2], A1[2][2], A2[2][2], A3[2][2];   // rotating A quads
    floatx4 acc[4][2][4];                      // [quad][mfrag][nfrag]
    #pragma unroll
    for (int q = 0; q < 4; ++q)
        #pragma unroll
        for (int f = 0; f < 2; ++f)
            #pragma unroll
            for (int n = 0; n < 4; ++n) acc[q][f][n] = (floatx4)0.0f;

    auto stage = [&](const bf16* src, bf16* dstBase, int t, int h) {
        const bf16* s = src + (size_t)h * K128 + (size_t)t * 64;
        bf16* d = dstBase + h * 8192 + stbase;
        gload_lds16(s, d);
        gload_lds16(s + K64, d + 4096);
    };
    auto ldA = [&](bf16x8 (&q)[2][2], const bf16* Asb, int f0) {
        #pragma unroll
        for (int f = 0; f < 2; ++f) {
            const bf16* p = Asb + ard + (f0 + f) * (16 * 64);
            q[f][0] = *(const bf16x8*)(p + sl0);
            q[f][1] = *(const bf16x8*)(p + sl1);
        }
    };
    auto ldB = [&](const bf16* Bsb) {
        #pragma unroll
        for (int n = 0; n < 4; ++n) {
            const bf16* p = Bsb + brd + n * (16 * 64);
            Bf[n][0] = *(const bf16x8*)(p + sl0);
            Bf[n][1] = *(const bf16x8*)(p + sl1);
        }
    };
    auto mm = [&](floatx4 (&ac)[2][4], bf16x8 (&a)[2][2]) {
        __builtin_amdgcn_s_setprio(1);
        #pragma unroll
        for (int f = 0; f < 2; ++f)
            #pragma unroll
            for (int n = 0; n < 4; ++n) {
                ac[f][n] = __builtin_amdgcn_mfma_f32_16x16x32_bf16(a[f][0], Bf[n][0], ac[f][n], 0, 0, 0);
                ac[f][n] = __builtin_amdgcn_mfma_f32_16x16x32_bf16(a[f][1], Bf[n][1], ac[f][n], 0, 0, 0);
            }
        __builtin_amdgcn_s_setprio(0);
    };

    const int NT = K >> 6;   // 32 for K=2048

    // prologue: tile0 fully + tile1 {Bh0,Bh1,Ah0}; VMC6 => tile0 landed
    stage(aSrc, smem[0],         0, 0);
    stage(aSrc, smem[0],         0, 1);
    stage(bSrc, smem[0] + 16384, 0, 0);
    stage(bSrc, smem[0] + 16384, 0, 1);
    stage(bSrc, smem[1] + 16384, 1, 0);
    stage(bSrc, smem[1] + 16384, 1, 1);
    stage(aSrc, smem[1],         1, 0);
    VMC6();
    BAR();
    // tail-pattern reads for tile 0: B(0) + quad0(0)
    ldB(smem[0] + 16384);
    ldA(A0, smem[0], 0);
    SCHED0();

    for (int t = 0; t < NT - 2; ++t) {
        const int b = t & 1;
        const bf16* Acur = smem[b];
        bf16* Awr = smem[b];
        bf16* Bwr = smem[b] + 16384;
        bf16* Aoth = smem[b ^ 1];
        const bf16* Anxt = smem[b ^ 1];
        const bf16* Bnxt = smem[b ^ 1] + 16384;
        // p0: read q1(t); stage Ah1(t+1); wait B+q0; mm0
        ldA(A1, Acur, 2);
        stage(aSrc, Aoth, t + 1, 1);
        SCHED0(); BAR(); LGKMC(4); SCHED0();
        mm(acc[0], A0);
        BAR();
        // p1: read q2(t); stage Bh0(t+2); wait q1; mm1
        ldA(A2, Acur, 4);
        stage(bSrc, Bwr, t + 2, 0);
        SCHED0(); BAR(); LGKMC(4); SCHED0();
        mm(acc[1], A1);
        BAR();
        // p2: read q3(t); stage Bh1(t+2); wait q2; mm2
        ldA(A3, Acur, 6);
        stage(bSrc, Bwr, t + 2, 1);
        SCHED0(); BAR(); LGKMC(4); SCHED0();
        mm(acc[2], A2);
        BAR();
        // p3: stage Ah0(t+2); VMC6 => tile t+1 landed; wait q3; mm3;
        // then tail reads for t+1 into dead registers
        stage(aSrc, Awr, t + 2, 0);
        VMC6();
        BAR(); LGKMC(0); SCHED0();
        mm(acc[3], A3);
        SCHED0();
        ldB(Bnxt);
        ldA(A0, Anxt, 0);
        SCHED0(); BAR();
    }
    {   // tile NT-2: stage only Ah1(NT-1); drain vmcnt to 0 at p3
        const int t = NT - 2;
        const int b = t & 1;
        const bf16* Acur = smem[b];
        bf16* Aoth = smem[b ^ 1];
        const bf16* Anxt = smem[b ^ 1];
        const bf16* Bnxt = smem[b ^ 1] + 16384;
        ldA(A1, Acur, 2);
        stage(aSrc, Aoth, t + 1, 1);
        SCHED0(); BAR(); LGKMC(4); SCHED0();
        mm(acc[0], A0);
        BAR();
        ldA(A2, Acur, 4);
        SCHED0(); BAR(); LGKMC(4); SCHED0();
        mm(acc[1], A1);
        BAR();
        ldA(A3, Acur, 6);
        SCHED0(); BAR(); LGKMC(4); SCHED0();
        mm(acc[2], A2);
        BAR();
        VMC0();                       // 8 outstanding -> tile NT-1 fully lands
        BAR(); LGKMC(0); SCHED0();
        mm(acc[3], A3);
        SCHED0();
        ldB(Bnxt);
        ldA(A0, Anxt, 0);
        SCHED0(); BAR();
    }
    {   // tile NT-1: no staging, no vmcnt
        const int b = (NT - 1) & 1;
        const bf16* Acur = smem[b];
        ldA(A1, Acur, 2);
        SCHED0(); BAR(); LGKMC(4); SCHED0();
        mm(acc[0], A0);
        BAR();
        ldA(A2, Acur, 4);
        SCHED0(); BAR(); LGKMC(4); SCHED0();
        mm(acc[1], A1);
        BAR();
        ldA(A3, Acur, 6);
        SCHED0(); BAR(); LGKMC(4); SCHED0();
        mm(acc[2], A2);
        BAR();
        LGKMC(0); SCHED0();
        mm(acc[3], A3);
    }

    // epilogue: C/D map col=lane&15, row=quad*4+reg
    #pragma unroll
    for (int q2 = 0; q2 < 4; ++q2)
        #pragma unroll
        for (int f = 0; f < 2; ++f)
            #pragma unroll
            for (int n = 0; n < 4; ++n) {
                const int c  = n0 + wn + n * 16 + col16;
                const int rb = m0 + wm + (q2 * 2 + f) * 16 + quad * 4;
                #pragma unroll
                for (int r = 0; r < 4; ++r) {
                    size_t off = (size_t)(rb + r) * N + c;
                    float v = acc[q2][f][n][r];
                    if (RESID) {
                        Fout[off] = resid[off] + scale[c] * v;
                    } else {
                        Hout[off] = (bf16)v;
                    }
                }
            }
}

extern "C" void kernel_launch(void* const* d_in, const int* in_sizes, int n_in,
                              void* d_out, int out_size, void* d_ws, size_t ws_size,
                              hipStream_t stream) {
    const float* x  = (const float*)d_in[0];
    const float* We = (const float*)d_in[1];
    const float* cw = (const float*)d_in[2];
    const float* cb = (const float*)d_in[3];
    const float* Wp = (const float*)d_in[4];
    const float* cs = (const float*)d_in[5];
    const int*   dil = (const int*)d_in[6];

    char* ws = (char*)d_ws;
    bf16* xn  = (bf16*)ws;                                  // 67108864 B (reused for o)
    bf16* Web = (bf16*)(ws + 67108864);                     // 25165824 B
    bf16* Wpb = (bf16*)(ws + 67108864 + 25165824);          // 8388608 B
    bf16* h   = (bf16*)(ws + 100663296);                    // 201326592 B

    f2bf_k<<<(3 * DIMD * DIMD / 4 + 255) / 256, 256, 0, stream>>>(We, Web, 3 * DIMD * DIMD);
    f2bf_k<<<(DIMD * DIMD / 4 + 255) / 256, 256, 0, stream>>>(Wp, Wpb, DIMD * DIMD);
    rmsnorm_k<<<MTOT, 256, 0, stream>>>(x, xn);
    gemm_bt<0><<<dim3(3 * DIMD / 256, MTOT / 256), 512, 0, stream>>>(
        xn, Web, h, nullptr, nullptr, nullptr, MTOT, 3 * DIMD, DIMD);
    gateconv_k<<<MTOT / 16, 256, 0, stream>>>(h, cw, cb, xn /*o*/, dil);
    gemm_bt<1><<<dim3(DIMD / 256, MTOT / 256), 512, 0, stream>>>(
        xn /*o*/, Wpb, nullptr, (float*)d_out, x, cs, MTOT, DIMD, DIMD);
}